// Round 2
// baseline (2375.826 us; speedup 1.0000x reference)
//
#include <hip/hip_runtime.h>
#include <hip/hip_bf16.h>

#define L_ROWS 8192
#define NUc 512
#define MH 4096      // L/2
#define KIN 1024     // 2*NU
#define NH 2048      // 4*NU
#define N_UNITS 25
#define CW 0.10897247358851332f
#define LN_EPS 1e-6f

typedef __bf16 bf16_t;
typedef __attribute__((ext_vector_type(8))) __bf16 bf16x8;
typedef __attribute__((ext_vector_type(4))) __bf16 bf16x4;
typedef __attribute__((ext_vector_type(4))) float f32x4;

#define GLD_LDS16(g, l) __builtin_amdgcn_global_load_lds( \
    (const __attribute__((address_space(1))) void*)(g),   \
    (__attribute__((address_space(3))) void*)(l), 16, 0, 0)

// ---------------------------------------------------------------- init
// sigmoid(rs) tables (fp32 inputs), zero the per-unit LN stats
__global__ void init_misc(const float* __restrict__ rs_f, const float* __restrict__ rs_r,
                          const float* __restrict__ rs_m,
                          float* __restrict__ sig, float* __restrict__ stats) {
    int i = blockIdx.x * 256 + threadIdx.x;           // 102,400 threads
    if (i < 3 * NUc) {
        const float* rs = (i < NUc) ? rs_f : (i < 2 * NUc ? rs_r : rs_m);
        float v = rs[i & (NUc - 1)];
        sig[i] = 1.0f / (1.0f + expf(-v));
    }
    if (i < N_UNITS * 2 * NH) stats[i] = 0.0f;
}

// ---------------------------------------------------------------- transpose
// out[C][R] (bf16) = in[R][C] (fp32), R,C multiples of 32
__global__ void transpose_f32_bf16(const float* __restrict__ in, bf16_t* __restrict__ out,
                                   int R, int C) {
    __shared__ float t[32][33];
    int lx = threadIdx.x & 31, ly = threadIdx.x >> 5;   // 32 x 8
    int bx = blockIdx.x, by = blockIdx.y;
#pragma unroll
    for (int s = 0; s < 32; s += 8) {
        int r = by * 32 + ly + s, c = bx * 32 + lx;
        t[ly + s][lx] = in[(size_t)r * C + c];
    }
    __syncthreads();
#pragma unroll
    for (int s = 0; s < 32; s += 8) {
        int r = bx * 32 + ly + s, c = by * 32 + lx;     // output coords
        out[(size_t)r * R + c] = (__bf16)t[lx][ly + s];
    }
}

// ---------------------------------------------------------------- GEMM1
// H[MH x NH] = A[MH x KIN](fp32) @ W1  (Bt = W1^T, NH x KIN, bf16)
// also accumulates per-column sum / sumsq of H into colsum[0..NH) / [NH..2NH)
__launch_bounds__(256, 2)
__global__ void gemm1_kernel(const float* __restrict__ A,
                             const bf16_t* __restrict__ Bt,
                             bf16_t* __restrict__ H,
                             float* __restrict__ colsum) {
    __shared__ __align__(16) bf16_t As[128 * 32];
    __shared__ __align__(16) bf16_t Bs[128 * 32];
    const int tid = threadIdx.x;
    const int wave = tid >> 6, lane = tid & 63;
    const int l16 = lane & 15, quad = lane >> 4;
    const int wm = wave >> 1, wn = wave & 1;
    const int bm0 = blockIdx.y * 128, bn0 = blockIdx.x * 128;

    f32x4 acc[4][4];
#pragma unroll
    for (int i = 0; i < 4; ++i)
#pragma unroll
        for (int j = 0; j < 4; ++j) acc[i][j] = (f32x4)(0.0f);

    for (int k0 = 0; k0 < KIN; k0 += 32) {
        // stage B (bf16) via async direct-to-LDS: 8 segments of 16 rows
#pragma unroll
        for (int s = wave; s < 8; s += 4) {
            const bf16_t* src = Bt + (size_t)(bn0 + s * 16 + (lane >> 2)) * KIN + k0 + (lane & 3) * 8;
            GLD_LDS16(src, Bs + s * 512 + lane * 8);
        }
        // stage A: fp32 -> bf16 via VGPRs
#pragma unroll
        for (int q = 0; q < 4; ++q) {
            int idx = q * 256 + tid;
            int r = idx >> 3, cg = (idx & 7) << 2;
            const float4 v = *(const float4*)(A + (size_t)(bm0 + r) * KIN + k0 + cg);
            bf16x4 p;
            p[0] = (__bf16)v.x; p[1] = (__bf16)v.y; p[2] = (__bf16)v.z; p[3] = (__bf16)v.w;
            *(bf16x4*)(As + r * 32 + cg) = p;
        }
        __syncthreads();
        bf16x8 a[4], b[4];
#pragma unroll
        for (int i = 0; i < 4; ++i)
            a[i] = *(const bf16x8*)(As + (wm * 64 + i * 16 + l16) * 32 + quad * 8);
#pragma unroll
        for (int j = 0; j < 4; ++j)
            b[j] = *(const bf16x8*)(Bs + (wn * 64 + j * 16 + l16) * 32 + quad * 8);
#pragma unroll
        for (int i = 0; i < 4; ++i)
#pragma unroll
            for (int j = 0; j < 4; ++j)
                acc[i][j] = __builtin_amdgcn_mfma_f32_16x16x32_bf16(b[j], a[i], acc[i][j], 0, 0, 0);
        __syncthreads();
    }

    // epilogue: swapped-operand layout -> lane holds row m = ...+l16, cols n0..n0+3
#pragma unroll
    for (int i = 0; i < 4; ++i) {
        int m = bm0 + wm * 64 + i * 16 + l16;
#pragma unroll
        for (int j = 0; j < 4; ++j) {
            int n = bn0 + wn * 64 + j * 16 + (quad << 2);
            bf16x4 p;
#pragma unroll
            for (int r = 0; r < 4; ++r) p[r] = (__bf16)acc[i][j][r];
            *(bf16x4*)(H + (size_t)m * NH + n) = p;
        }
    }
    // column stats: reduce 4 i-tiles + 16 l16 lanes, then atomics
#pragma unroll
    for (int j = 0; j < 4; ++j) {
#pragma unroll
        for (int r = 0; r < 4; ++r) {
            float s1 = 0.f, s2 = 0.f;
#pragma unroll
            for (int i = 0; i < 4; ++i) { float v = acc[i][j][r]; s1 += v; s2 += v * v; }
#pragma unroll
            for (int msk = 1; msk < 16; msk <<= 1) {
                s1 += __shfl_xor(s1, msk);
                s2 += __shfl_xor(s2, msk);
            }
            if (l16 == 0) {
                int n = bn0 + wn * 64 + j * 16 + (quad << 2) + r;
                atomicAdd(&colsum[n], s1);
                atomicAdd(&colsum[NH + n], s2);
            }
        }
    }
}

// ---------------------------------------------------------------- normalize
// H <- leaky_relu((H - mean) * rsqrt(var + eps)), per-column stats
__global__ void norm_kernel(bf16_t* __restrict__ H, const float* __restrict__ stats) {
    int idx = blockIdx.x * 256 + threadIdx.x;          // 1,048,576 octets
    bf16x8 h = *(bf16x8*)(H + (size_t)idx * 8);
    int col = (idx * 8) & (NH - 1);
#pragma unroll
    for (int t = 0; t < 8; ++t) {
        float s1 = stats[col + t], s2 = stats[NH + col + t];
        float mean = s1 * (1.0f / MH);
        float var = s2 * (1.0f / MH) - mean * mean;
        float rstd = rsqrtf(var + LN_EPS);
        float v = ((float)h[t] - mean) * rstd;
        v = v > 0.f ? v : 0.2f * v;
        h[t] = (__bf16)v;
    }
    *(bf16x8*)(H + (size_t)idx * 8) = h;
}

// ---------------------------------------------------------------- GEMM2
// C[MH x KIN] = Hn[MH x NH] @ W2 (Bt = W2^T, KIN x NH); fused residual + perm scatter
__launch_bounds__(256, 2)
__global__ void gemm2_kernel(const bf16_t* __restrict__ Hn,
                             const bf16_t* __restrict__ Bt,
                             const float* __restrict__ yin,
                             float* __restrict__ yout,
                             const float* __restrict__ sig,
                             const float* __restrict__ b2,
                             int mode) {
    __shared__ __align__(16) bf16_t As[128 * 32];
    __shared__ __align__(16) bf16_t Bs[64 * 32];
    const int tid = threadIdx.x;
    const int wave = tid >> 6, lane = tid & 63;
    const int l16 = lane & 15, quad = lane >> 4;
    const int wm = wave >> 1, wn = wave & 1;
    const int bm0 = blockIdx.y * 128, bn0 = blockIdx.x * 64;

    f32x4 acc[4][2];
#pragma unroll
    for (int i = 0; i < 4; ++i)
#pragma unroll
        for (int j = 0; j < 2; ++j) acc[i][j] = (f32x4)(0.0f);

    for (int k0 = 0; k0 < NH; k0 += 32) {
#pragma unroll
        for (int s = wave; s < 8; s += 4) {
            const bf16_t* src = Hn + (size_t)(bm0 + s * 16 + (lane >> 2)) * NH + k0 + (lane & 3) * 8;
            GLD_LDS16(src, As + s * 512 + lane * 8);
        }
        {
            const bf16_t* src = Bt + (size_t)(bn0 + wave * 16 + (lane >> 2)) * NH + k0 + (lane & 3) * 8;
            GLD_LDS16(src, Bs + wave * 512 + lane * 8);
        }
        __syncthreads();
        bf16x8 a[4], b[2];
#pragma unroll
        for (int i = 0; i < 4; ++i)
            a[i] = *(const bf16x8*)(As + (wm * 64 + i * 16 + l16) * 32 + quad * 8);
#pragma unroll
        for (int j = 0; j < 2; ++j)
            b[j] = *(const bf16x8*)(Bs + (wn * 32 + j * 16 + l16) * 32 + quad * 8);
#pragma unroll
        for (int i = 0; i < 4; ++i)
#pragma unroll
            for (int j = 0; j < 2; ++j)
                acc[i][j] = __builtin_amdgcn_mfma_f32_16x16x32_bf16(b[j], a[i], acc[i][j], 0, 0, 0);
        __syncthreads();
    }

    // epilogue: bias, residual, permutation scatter (fp32 out)
#pragma unroll
    for (int i = 0; i < 4; ++i) {
        int m = bm0 + wm * 64 + i * 16 + l16;
#pragma unroll
        for (int j = 0; j < 2; ++j) {
            int n0 = bn0 + wn * 32 + j * 16 + (quad << 2);
            int yrow = 2 * m + (n0 >> 9);
            int ycol = n0 & (NUc - 1);
            float sgv[4]; *(float4*)sgv = *(const float4*)(sig + ycol);
            float yv[4];  *(float4*)yv  = *(const float4*)(yin + (size_t)yrow * NUc + ycol);
            float bb[4];  *(float4*)bb  = *(const float4*)(b2 + n0);
            int dest = (mode == 0) ? ((yrow < MH) ? 2 * yrow : 2 * yrow - (L_ROWS - 1))
                     : (mode == 1) ? (((yrow & 1) ? MH + (yrow >> 1) : (yrow >> 1)))
                     : yrow;
            float o[4];
#pragma unroll
            for (int r = 0; r < 4; ++r)
                o[r] = sgv[r] * yv[r] + (acc[i][j][r] + bb[r]) * CW;
            *(float4*)(yout + (size_t)dest * NUc + ycol) = *(float4*)o;
        }
    }
}

// ---------------------------------------------------------------- launch
extern "C" void kernel_launch(void* const* d_in, const int* in_sizes, int n_in,
                              void* d_out, int out_size, void* d_ws, size_t ws_size,
                              hipStream_t stream) {
    (void)in_sizes; (void)n_in; (void)out_size; (void)ws_size;
    const float* x    = (const float*)d_in[0];
    const float* rs_f = (const float*)d_in[1];
    const float* w1[3] = {(const float*)d_in[2], (const float*)d_in[6], (const float*)d_in[10]};
    const float* w2[3] = {(const float*)d_in[3], (const float*)d_in[7], (const float*)d_in[11]};
    const float* b2[3] = {(const float*)d_in[4], (const float*)d_in[8], (const float*)d_in[12]};
    const float* rs_r = (const float*)d_in[5];
    const float* rs_m = (const float*)d_in[9];

    // workspace layout (~72.5 MB)
    float*  y0    = (float*)d_ws;                          // 4M fp32
    float*  y1    = y0 + (size_t)MH * KIN;                 // 4M fp32
    bf16_t* H     = (bf16_t*)(y1 + (size_t)MH * KIN);      // 8M bf16
    bf16_t* w1t   = H + (size_t)MH * NH;                   // 3 x 2M bf16
    bf16_t* w2t   = w1t + 3 * (size_t)NH * KIN;            // 3 x 2M bf16
    float*  sig   = (float*)(w2t + 3 * (size_t)KIN * NH);  // 1536 fp32
    float*  stats = sig + 3 * NUc;                         // 25 x 2 x 2048 fp32

    init_misc<<<400, 256, 0, stream>>>(rs_f, rs_r, rs_m, sig, stats);
    for (int t = 0; t < 3; ++t) {
        // w1 (KIN x NH, fp32) -> w1t (NH x KIN, bf16)
        transpose_f32_bf16<<<dim3(NH / 32, KIN / 32), 256, 0, stream>>>(w1[t], w1t + (size_t)t * NH * KIN, KIN, NH);
        // w2 (NH x KIN, fp32) -> w2t (KIN x NH, bf16)
        transpose_f32_bf16<<<dim3(KIN / 32, NH / 32), 256, 0, stream>>>(w2[t], w2t + (size_t)t * KIN * NH, NH, KIN);
    }

    const float* cur = x;
    float* bufs[2] = {y0, y1};
    for (int u = 0; u < N_UNITS; ++u) {
        int tag  = (u < 12) ? 0 : (u < 24 ? 1 : 2);
        int mode = (u < 12) ? 0 : (u < 24 ? 1 : 2);
        float* st = stats + (size_t)u * 2 * NH;
        float* out = (u == N_UNITS - 1) ? (float*)d_out : bufs[u & 1];
        gemm1_kernel<<<dim3(NH / 128, MH / 128), 256, 0, stream>>>(
            cur, w1t + (size_t)tag * NH * KIN, H, st);
        norm_kernel<<<4096, 256, 0, stream>>>(H, st);
        gemm2_kernel<<<dim3(KIN / 64, MH / 128), 256, 0, stream>>>(
            H, w2t + (size_t)tag * KIN * NH, cur, out,
            sig + tag * NUc, b2[tag], mode);
        cur = out;
    }
}

// Round 3
// 2371.253 us; speedup vs baseline: 1.0019x; 1.0019x over previous
//
#include <hip/hip_runtime.h>
#include <hip/hip_bf16.h>

#define L_ROWS 8192
#define NUc 512
#define MH 4096      // L/2
#define KIN 1024     // 2*NU
#define NH 2048      // 4*NU
#define N_UNITS 25
#define CW 0.10897247358851332f
#define LN_EPS 1e-6f

typedef __bf16 bf16_t;
typedef __attribute__((ext_vector_type(8))) __bf16 bf16x8;
typedef __attribute__((ext_vector_type(4))) __bf16 bf16x4;
typedef __attribute__((ext_vector_type(4))) float f32x4;

#define GLD_LDS16(g, l) __builtin_amdgcn_global_load_lds( \
    (const __attribute__((address_space(1))) void*)(g),   \
    (__attribute__((address_space(3))) void*)(l), 16, 0, 0)

// ---------------------------------------------------------------- init
// xb = bf16(x); sigmoid(rs) tables; zero LN stats
__global__ void init_misc(const float* __restrict__ x, bf16_t* __restrict__ xb,
                          const float* __restrict__ rs_f, const float* __restrict__ rs_r,
                          const float* __restrict__ rs_m,
                          float* __restrict__ sig, float* __restrict__ stats) {
    int i = blockIdx.x * 256 + threadIdx.x;           // 1,048,576 threads x 4 el
    {
        float4 v = *(const float4*)(x + (size_t)i * 4);
        bf16x4 p;
        p[0] = (__bf16)v.x; p[1] = (__bf16)v.y; p[2] = (__bf16)v.z; p[3] = (__bf16)v.w;
        *(bf16x4*)(xb + (size_t)i * 4) = p;
    }
    if (i < 3 * NUc) {
        const float* rs = (i < NUc) ? rs_f : (i < 2 * NUc ? rs_r : rs_m);
        float v = rs[i & (NUc - 1)];
        sig[i] = 1.0f / (1.0f + expf(-v));
    }
    if (i < N_UNITS * 2 * NH) stats[i] = 0.0f;
}

// ---------------------------------------------------------------- transpose
// out[C][R] (bf16) = in[R][C] (fp32), R,C multiples of 32
__global__ void transpose_f32_bf16(const float* __restrict__ in, bf16_t* __restrict__ out,
                                   int R, int C) {
    __shared__ float t[32][33];
    int lx = threadIdx.x & 31, ly = threadIdx.x >> 5;   // 32 x 8
    int bx = blockIdx.x, by = blockIdx.y;
#pragma unroll
    for (int s = 0; s < 32; s += 8) {
        int r = by * 32 + ly + s, c = bx * 32 + lx;
        t[ly + s][lx] = in[(size_t)r * C + c];
    }
    __syncthreads();
#pragma unroll
    for (int s = 0; s < 32; s += 8) {
        int r = bx * 32 + ly + s, c = by * 32 + lx;     // output coords
        out[(size_t)r * R + c] = (__bf16)t[lx][ly + s];
    }
}

// ---------------------------------------------------------------- GEMM1
// H[MH x NH] = Ab[MH x KIN](bf16) @ W1 (Bt = W1^T, NH x KIN, bf16)
// tile 128(M) x 64(N), 4 waves of 32x64; also per-column sum/sumsq -> colsum
__launch_bounds__(256, 4)
__global__ void gemm1_kernel(const bf16_t* __restrict__ Ab,
                             const bf16_t* __restrict__ Bt,
                             bf16_t* __restrict__ H,
                             float* __restrict__ colsum) {
    __shared__ __align__(16) bf16_t As[128 * 32];
    __shared__ __align__(16) bf16_t Bs[64 * 32];
    const int tid = threadIdx.x;
    const int wave = tid >> 6, lane = tid & 63;
    const int l16 = lane & 15, quad = lane >> 4;
    const int bm0 = blockIdx.y * 128, bn0 = blockIdx.x * 64;

    f32x4 acc[2][4];
#pragma unroll
    for (int i = 0; i < 2; ++i)
#pragma unroll
        for (int j = 0; j < 4; ++j) acc[i][j] = (f32x4)(0.0f);

    const bf16_t* pa0 = Ab + (size_t)(bm0 + wave * 16 + (lane >> 2)) * KIN + (lane & 3) * 8;
    const bf16_t* pa1 = pa0 + (size_t)64 * KIN;
    const bf16_t* pb  = Bt + (size_t)(bn0 + wave * 16 + (lane >> 2)) * KIN + (lane & 3) * 8;
    bf16_t* la0 = As + wave * 512 + lane * 8;
    bf16_t* la1 = As + (wave + 4) * 512 + lane * 8;
    bf16_t* lb  = Bs + wave * 512 + lane * 8;

    for (int k0 = 0; k0 < KIN; k0 += 32) {
        GLD_LDS16(pa0 + k0, la0);
        GLD_LDS16(pa1 + k0, la1);
        GLD_LDS16(pb + k0, lb);
        __syncthreads();
        bf16x8 a[2], b[4];
#pragma unroll
        for (int i = 0; i < 2; ++i)
            a[i] = *(const bf16x8*)(As + (wave * 32 + i * 16 + l16) * 32 + quad * 8);
#pragma unroll
        for (int j = 0; j < 4; ++j)
            b[j] = *(const bf16x8*)(Bs + (j * 16 + l16) * 32 + quad * 8);
#pragma unroll
        for (int i = 0; i < 2; ++i)
#pragma unroll
            for (int j = 0; j < 4; ++j)
                acc[i][j] = __builtin_amdgcn_mfma_f32_16x16x32_bf16(b[j], a[i], acc[i][j], 0, 0, 0);
        __syncthreads();
    }

    // epilogue: lane holds row m, 4 consecutive cols
#pragma unroll
    for (int i = 0; i < 2; ++i) {
        int m = bm0 + wave * 32 + i * 16 + l16;
#pragma unroll
        for (int j = 0; j < 4; ++j) {
            int n = bn0 + j * 16 + (quad << 2);
            bf16x4 p;
#pragma unroll
            for (int r = 0; r < 4; ++r) p[r] = (__bf16)acc[i][j][r];
            *(bf16x4*)(H + (size_t)m * NH + n) = p;
        }
    }
    // column stats: reduce 2 i-tiles + 16 l16 lanes, then atomics
#pragma unroll
    for (int j = 0; j < 4; ++j) {
#pragma unroll
        for (int r = 0; r < 4; ++r) {
            float s1 = 0.f, s2 = 0.f;
#pragma unroll
            for (int i = 0; i < 2; ++i) { float v = acc[i][j][r]; s1 += v; s2 += v * v; }
#pragma unroll
            for (int msk = 1; msk < 16; msk <<= 1) {
                s1 += __shfl_xor(s1, msk);
                s2 += __shfl_xor(s2, msk);
            }
            if (l16 == 0) {
                int n = bn0 + j * 16 + (quad << 2) + r;
                atomicAdd(&colsum[n], s1);
                atomicAdd(&colsum[NH + n], s2);
            }
        }
    }
}

// ---------------------------------------------------------------- normalize
// H <- leaky_relu((H - mean) * rsqrt(var + eps)), per-column stats
__global__ void norm_kernel(bf16_t* __restrict__ H, const float* __restrict__ stats) {
    int idx = blockIdx.x * 256 + threadIdx.x;          // 1,048,576 octets
    bf16x8 h = *(bf16x8*)(H + (size_t)idx * 8);
    int col = (idx * 8) & (NH - 1);
#pragma unroll
    for (int t = 0; t < 8; ++t) {
        float s1 = stats[col + t], s2 = stats[NH + col + t];
        float mean = s1 * (1.0f / MH);
        float var = s2 * (1.0f / MH) - mean * mean;
        float rstd = rsqrtf(var + LN_EPS);
        float v = ((float)h[t] - mean) * rstd;
        v = v > 0.f ? v : 0.2f * v;
        h[t] = (__bf16)v;
    }
    *(bf16x8*)(H + (size_t)idx * 8) = h;
}

// ---------------------------------------------------------------- GEMM2
// C[MH x KIN] = Hn[MH x NH] @ W2 (Bt = W2^T, KIN x NH); fused residual + perm
// scatter; writes fp32 yout AND bf16 ybout (next unit's GEMM1 A operand)
__launch_bounds__(256, 4)
__global__ void gemm2_kernel(const bf16_t* __restrict__ Hn,
                             const bf16_t* __restrict__ Bt,
                             const float* __restrict__ yin,
                             float* __restrict__ yout,
                             bf16_t* __restrict__ ybout,
                             const float* __restrict__ sig,
                             const float* __restrict__ b2,
                             int mode) {
    __shared__ __align__(16) bf16_t As[128 * 32];
    __shared__ __align__(16) bf16_t Bs[64 * 32];
    const int tid = threadIdx.x;
    const int wave = tid >> 6, lane = tid & 63;
    const int l16 = lane & 15, quad = lane >> 4;
    const int bm0 = blockIdx.y * 128, bn0 = blockIdx.x * 64;

    f32x4 acc[2][4];
#pragma unroll
    for (int i = 0; i < 2; ++i)
#pragma unroll
        for (int j = 0; j < 4; ++j) acc[i][j] = (f32x4)(0.0f);

    const bf16_t* pa0 = Hn + (size_t)(bm0 + wave * 16 + (lane >> 2)) * NH + (lane & 3) * 8;
    const bf16_t* pa1 = pa0 + (size_t)64 * NH;
    const bf16_t* pb  = Bt + (size_t)(bn0 + wave * 16 + (lane >> 2)) * NH + (lane & 3) * 8;
    bf16_t* la0 = As + wave * 512 + lane * 8;
    bf16_t* la1 = As + (wave + 4) * 512 + lane * 8;
    bf16_t* lb  = Bs + wave * 512 + lane * 8;

    for (int k0 = 0; k0 < NH; k0 += 32) {
        GLD_LDS16(pa0 + k0, la0);
        GLD_LDS16(pa1 + k0, la1);
        GLD_LDS16(pb + k0, lb);
        __syncthreads();
        bf16x8 a[2], b[4];
#pragma unroll
        for (int i = 0; i < 2; ++i)
            a[i] = *(const bf16x8*)(As + (wave * 32 + i * 16 + l16) * 32 + quad * 8);
#pragma unroll
        for (int j = 0; j < 4; ++j)
            b[j] = *(const bf16x8*)(Bs + (j * 16 + l16) * 32 + quad * 8);
#pragma unroll
        for (int i = 0; i < 2; ++i)
#pragma unroll
            for (int j = 0; j < 4; ++j)
                acc[i][j] = __builtin_amdgcn_mfma_f32_16x16x32_bf16(b[j], a[i], acc[i][j], 0, 0, 0);
        __syncthreads();
    }

    // epilogue: bias, residual, permutation scatter (fp32 + bf16 copies)
#pragma unroll
    for (int i = 0; i < 2; ++i) {
        int m = bm0 + wave * 32 + i * 16 + l16;
#pragma unroll
        for (int j = 0; j < 4; ++j) {
            int n0 = bn0 + j * 16 + (quad << 2);
            int yrow = 2 * m + (n0 >> 9);
            int ycol = n0 & (NUc - 1);
            float sgv[4]; *(float4*)sgv = *(const float4*)(sig + ycol);
            float yv[4];  *(float4*)yv  = *(const float4*)(yin + (size_t)yrow * NUc + ycol);
            float bb[4];  *(float4*)bb  = *(const float4*)(b2 + n0);
            int dest = (mode == 0) ? ((yrow < MH) ? 2 * yrow : 2 * yrow - (L_ROWS - 1))
                     : (mode == 1) ? (((yrow & 1) ? MH + (yrow >> 1) : (yrow >> 1)))
                     : yrow;
            float o[4];
            bf16x4 q;
#pragma unroll
            for (int r = 0; r < 4; ++r) {
                o[r] = sgv[r] * yv[r] + (acc[i][j][r] + bb[r]) * CW;
                q[r] = (__bf16)o[r];
            }
            *(float4*)(yout + (size_t)dest * NUc + ycol) = *(float4*)o;
            *(bf16x4*)(ybout + (size_t)dest * NUc + ycol) = q;
        }
    }
}

// ---------------------------------------------------------------- launch
extern "C" void kernel_launch(void* const* d_in, const int* in_sizes, int n_in,
                              void* d_out, int out_size, void* d_ws, size_t ws_size,
                              hipStream_t stream) {
    (void)in_sizes; (void)n_in; (void)out_size; (void)ws_size;
    const float* x    = (const float*)d_in[0];
    const float* rs_f = (const float*)d_in[1];
    const float* w1[3] = {(const float*)d_in[2], (const float*)d_in[6], (const float*)d_in[10]};
    const float* w2[3] = {(const float*)d_in[3], (const float*)d_in[7], (const float*)d_in[11]};
    const float* b2[3] = {(const float*)d_in[4], (const float*)d_in[8], (const float*)d_in[12]};
    const float* rs_r = (const float*)d_in[5];
    const float* rs_m = (const float*)d_in[9];

    // workspace layout (~84 MB)
    float*  y0    = (float*)d_ws;                          // 4M fp32
    float*  y1    = y0 + (size_t)MH * KIN;                 // 4M fp32
    bf16_t* yb    = (bf16_t*)(y1 + (size_t)MH * KIN);      // 4M bf16
    bf16_t* H     = yb + (size_t)MH * KIN;                 // 8M bf16
    bf16_t* w1t   = H + (size_t)MH * NH;                   // 3 x 2M bf16
    bf16_t* w2t   = w1t + 3 * (size_t)NH * KIN;            // 3 x 2M bf16
    float*  sig   = (float*)(w2t + 3 * (size_t)KIN * NH);  // 1536 fp32
    float*  stats = sig + 3 * NUc;                         // 25 x 2 x 2048 fp32

    init_misc<<<4096, 256, 0, stream>>>(x, yb, rs_f, rs_r, rs_m, sig, stats);
    for (int t = 0; t < 3; ++t) {
        transpose_f32_bf16<<<dim3(NH / 32, KIN / 32), 256, 0, stream>>>(w1[t], w1t + (size_t)t * NH * KIN, KIN, NH);
        transpose_f32_bf16<<<dim3(KIN / 32, NH / 32), 256, 0, stream>>>(w2[t], w2t + (size_t)t * KIN * NH, NH, KIN);
    }

    const float* cur = x;
    float* bufs[2] = {y0, y1};
    for (int u = 0; u < N_UNITS; ++u) {
        int tag  = (u < 12) ? 0 : (u < 24 ? 1 : 2);
        int mode = (u < 12) ? 0 : (u < 24 ? 1 : 2);
        float* st = stats + (size_t)u * 2 * NH;
        float* out = (u == N_UNITS - 1) ? (float*)d_out : bufs[u & 1];
        gemm1_kernel<<<dim3(NH / 64, MH / 128), 256, 0, stream>>>(
            yb, w1t + (size_t)tag * NH * KIN, H, st);
        norm_kernel<<<4096, 256, 0, stream>>>(H, st);
        gemm2_kernel<<<dim3(KIN / 64, MH / 128), 256, 0, stream>>>(
            H, w2t + (size_t)tag * KIN * NH, cur, out, yb,
            sig + tag * NUc, b2[tag], mode);
        cur = out;
    }
}

// Round 4
// 1858.938 us; speedup vs baseline: 1.2781x; 1.2756x over previous
//
#include <hip/hip_runtime.h>
#include <hip/hip_bf16.h>

#define L_ROWS 8192
#define NUc 512
#define MH 4096      // L/2
#define KIN 1024     // 2*NU
#define NH 2048      // 4*NU
#define N_UNITS 25
#define CW 0.10897247358851332f
#define LN_EPS 1e-6f

typedef __bf16 bf16_t;
typedef __attribute__((ext_vector_type(8))) __bf16 bf16x8;
typedef __attribute__((ext_vector_type(4))) __bf16 bf16x4;
typedef __attribute__((ext_vector_type(4))) float f32x4;

#define GLD_LDS16(g, l) __builtin_amdgcn_global_load_lds( \
    (const __attribute__((address_space(1))) void*)(g),   \
    (__attribute__((address_space(3))) void*)(l), 16, 0, 0)

// LDS layout for BK=64 tiles: row stride 64 elems (128 B). 16B-unit u of row r
// is stored at physical unit (u ^ (r & 7)) — XOR swizzle applied on the global
// source address per lane, so ds_read_b128 of a column-slice hits 8 distinct
// 4-bank groups (2-way only, free) instead of a 16-way conflict.

// ---------------------------------------------------------------- init
__global__ void init_misc(const float* __restrict__ x, bf16_t* __restrict__ xb,
                          const float* __restrict__ rs_f, const float* __restrict__ rs_r,
                          const float* __restrict__ rs_m,
                          float* __restrict__ sig, float* __restrict__ stats) {
    int i = blockIdx.x * 256 + threadIdx.x;           // 1,048,576 threads x 4 el
    {
        float4 v = *(const float4*)(x + (size_t)i * 4);
        bf16x4 p;
        p[0] = (__bf16)v.x; p[1] = (__bf16)v.y; p[2] = (__bf16)v.z; p[3] = (__bf16)v.w;
        *(bf16x4*)(xb + (size_t)i * 4) = p;
    }
    if (i < 3 * NUc) {
        const float* rs = (i < NUc) ? rs_f : (i < 2 * NUc ? rs_r : rs_m);
        float v = rs[i & (NUc - 1)];
        sig[i] = 1.0f / (1.0f + expf(-v));
    }
    if (i < N_UNITS * 2 * NH) stats[i] = 0.0f;
}

// ---------------------------------------------------------------- transpose
__global__ void transpose_f32_bf16(const float* __restrict__ in, bf16_t* __restrict__ out,
                                   int R, int C) {
    __shared__ float t[32][33];
    int lx = threadIdx.x & 31, ly = threadIdx.x >> 5;   // 32 x 8
    int bx = blockIdx.x, by = blockIdx.y;
#pragma unroll
    for (int s = 0; s < 32; s += 8) {
        int r = by * 32 + ly + s, c = bx * 32 + lx;
        t[ly + s][lx] = in[(size_t)r * C + c];
    }
    __syncthreads();
#pragma unroll
    for (int s = 0; s < 32; s += 8) {
        int r = bx * 32 + ly + s, c = by * 32 + lx;
        out[(size_t)r * R + c] = (__bf16)t[lx][ly + s];
    }
}

// ---------------------------------------------------------------- GEMM1
// H[MH x NH] = Ab[MH x KIN](bf16) @ W1 (Bt = W1^T, NH x KIN, bf16)
// tile 128(M) x 64(N), BK=64, 4 waves in 2x2 split (64x32 wave-tiles)
__launch_bounds__(256, 4)
__global__ void gemm1_kernel(const bf16_t* __restrict__ Ab,
                             const bf16_t* __restrict__ Bt,
                             bf16_t* __restrict__ H,
                             float* __restrict__ colsum) {
    __shared__ __align__(16) bf16_t As[128 * 64];
    __shared__ __align__(16) bf16_t Bs[64 * 64];
    const int tid = threadIdx.x;
    const int wave = tid >> 6, lane = tid & 63;
    const int l16 = lane & 15, quad = lane >> 4;
    const int wm = wave >> 1, wn = wave & 1;
    const int bm0 = blockIdx.y * 128, bn0 = blockIdx.x * 64;

    f32x4 acc[4][2];
#pragma unroll
    for (int i = 0; i < 4; ++i)
#pragma unroll
        for (int j = 0; j < 2; ++j) acc[i][j] = (f32x4)(0.0f);

    const int rin = lane >> 3, usrc = (lane & 7) ^ (rin & 7);
    const bf16_t* pa = Ab + (size_t)(bm0 + wave * 8 + rin) * KIN + usrc * 8;
    const bf16_t* pb = Bt + (size_t)(bn0 + wave * 8 + rin) * KIN + usrc * 8;
    bf16_t* la = As + wave * 512 + lane * 8;
    bf16_t* lb = Bs + wave * 512 + lane * 8;
    const int sw = (l16 & 7) * 8;   // ds_read swizzle offset base

    for (int k0 = 0; k0 < KIN; k0 += 64) {
#pragma unroll
        for (int s = 0; s < 4; ++s)   // A: segs wave+4s (rows 32s..)
            GLD_LDS16(pa + (size_t)(s * 32) * KIN + k0, la + s * 2048);
#pragma unroll
        for (int s = 0; s < 2; ++s)   // B: segs wave+4s
            GLD_LDS16(pb + (size_t)(s * 32) * KIN + k0, lb + s * 2048);
        __syncthreads();
        bf16x8 a[4][2], b[2][2];
#pragma unroll
        for (int h = 0; h < 2; ++h) {
            int u = ((h * 4 + quad) * 8) ^ sw;
#pragma unroll
            for (int i = 0; i < 4; ++i)
                a[i][h] = *(const bf16x8*)(As + (wm * 64 + i * 16 + l16) * 64 + u);
#pragma unroll
            for (int j = 0; j < 2; ++j)
                b[j][h] = *(const bf16x8*)(Bs + (wn * 32 + j * 16 + l16) * 64 + u);
        }
#pragma unroll
        for (int h = 0; h < 2; ++h)
#pragma unroll
            for (int i = 0; i < 4; ++i)
#pragma unroll
                for (int j = 0; j < 2; ++j)
                    acc[i][j] = __builtin_amdgcn_mfma_f32_16x16x32_bf16(b[j][h], a[i][h], acc[i][j], 0, 0, 0);
        __syncthreads();
    }

    // epilogue: lane holds row m, 4 consecutive cols
#pragma unroll
    for (int i = 0; i < 4; ++i) {
        int m = bm0 + wm * 64 + i * 16 + l16;
#pragma unroll
        for (int j = 0; j < 2; ++j) {
            int n = bn0 + wn * 32 + j * 16 + (quad << 2);
            bf16x4 p;
#pragma unroll
            for (int r = 0; r < 4; ++r) p[r] = (__bf16)acc[i][j][r];
            *(bf16x4*)(H + (size_t)m * NH + n) = p;
        }
    }
    // column stats: reduce 4 i-tiles + 16 l16 lanes, then atomics
#pragma unroll
    for (int j = 0; j < 2; ++j) {
#pragma unroll
        for (int r = 0; r < 4; ++r) {
            float s1 = 0.f, s2 = 0.f;
#pragma unroll
            for (int i = 0; i < 4; ++i) { float v = acc[i][j][r]; s1 += v; s2 += v * v; }
#pragma unroll
            for (int msk = 1; msk < 16; msk <<= 1) {
                s1 += __shfl_xor(s1, msk);
                s2 += __shfl_xor(s2, msk);
            }
            if (l16 == 0) {
                int n = bn0 + wn * 32 + j * 16 + (quad << 2) + r;
                atomicAdd(&colsum[n], s1);
                atomicAdd(&colsum[NH + n], s2);
            }
        }
    }
}

// ---------------------------------------------------------------- normalize
__global__ void norm_kernel(bf16_t* __restrict__ H, const float* __restrict__ stats) {
    int idx = blockIdx.x * 256 + threadIdx.x;          // 1,048,576 octets
    bf16x8 h = *(bf16x8*)(H + (size_t)idx * 8);
    int col = (idx * 8) & (NH - 1);
#pragma unroll
    for (int t = 0; t < 8; ++t) {
        float s1 = stats[col + t], s2 = stats[NH + col + t];
        float mean = s1 * (1.0f / MH);
        float var = s2 * (1.0f / MH) - mean * mean;
        float rstd = rsqrtf(var + LN_EPS);
        float v = ((float)h[t] - mean) * rstd;
        v = v > 0.f ? v : 0.2f * v;
        h[t] = (__bf16)v;
    }
    *(bf16x8*)(H + (size_t)idx * 8) = h;
}

// ---------------------------------------------------------------- GEMM2
// C[MH x KIN] = Hn[MH x NH] @ W2 (Bt = W2^T, KIN x NH); tile 128x64, BK=64,
// 2x2 wave split; fused residual + perm scatter; fp32 yout + bf16 ybout
__launch_bounds__(256, 2)
__global__ void gemm2_kernel(const bf16_t* __restrict__ Hn,
                             const bf16_t* __restrict__ Bt,
                             const float* __restrict__ yin,
                             float* __restrict__ yout,
                             bf16_t* __restrict__ ybout,
                             const float* __restrict__ sig,
                             const float* __restrict__ b2,
                             int mode) {
    __shared__ __align__(16) bf16_t As[128 * 64];
    __shared__ __align__(16) bf16_t Bs[64 * 64];
    const int tid = threadIdx.x;
    const int wave = tid >> 6, lane = tid & 63;
    const int l16 = lane & 15, quad = lane >> 4;
    const int wm = wave >> 1, wn = wave & 1;
    const int bm0 = blockIdx.y * 128, bn0 = blockIdx.x * 64;

    f32x4 acc[4][2];
#pragma unroll
    for (int i = 0; i < 4; ++i)
#pragma unroll
        for (int j = 0; j < 2; ++j) acc[i][j] = (f32x4)(0.0f);

    const int rin = lane >> 3, usrc = (lane & 7) ^ (rin & 7);
    const bf16_t* pa = Hn + (size_t)(bm0 + wave * 8 + rin) * NH + usrc * 8;
    const bf16_t* pb = Bt + (size_t)(bn0 + wave * 8 + rin) * NH + usrc * 8;
    bf16_t* la = As + wave * 512 + lane * 8;
    bf16_t* lb = Bs + wave * 512 + lane * 8;
    const int sw = (l16 & 7) * 8;

    for (int k0 = 0; k0 < NH; k0 += 64) {
#pragma unroll
        for (int s = 0; s < 4; ++s)
            GLD_LDS16(pa + (size_t)(s * 32) * NH + k0, la + s * 2048);
#pragma unroll
        for (int s = 0; s < 2; ++s)
            GLD_LDS16(pb + (size_t)(s * 32) * NH + k0, lb + s * 2048);
        __syncthreads();
        bf16x8 a[4][2], b[2][2];
#pragma unroll
        for (int h = 0; h < 2; ++h) {
            int u = ((h * 4 + quad) * 8) ^ sw;
#pragma unroll
            for (int i = 0; i < 4; ++i)
                a[i][h] = *(const bf16x8*)(As + (wm * 64 + i * 16 + l16) * 64 + u);
#pragma unroll
            for (int j = 0; j < 2; ++j)
                b[j][h] = *(const bf16x8*)(Bs + (wn * 32 + j * 16 + l16) * 64 + u);
        }
#pragma unroll
        for (int h = 0; h < 2; ++h)
#pragma unroll
            for (int i = 0; i < 4; ++i)
#pragma unroll
                for (int j = 0; j < 2; ++j)
                    acc[i][j] = __builtin_amdgcn_mfma_f32_16x16x32_bf16(b[j][h], a[i][h], acc[i][j], 0, 0, 0);
        __syncthreads();
    }

    // epilogue: bias, residual, permutation scatter (fp32 + bf16 copies)
#pragma unroll
    for (int i = 0; i < 4; ++i) {
        int m = bm0 + wm * 64 + i * 16 + l16;
#pragma unroll
        for (int j = 0; j < 2; ++j) {
            int n0 = bn0 + wn * 32 + j * 16 + (quad << 2);
            int yrow = 2 * m + (n0 >> 9);
            int ycol = n0 & (NUc - 1);
            float sgv[4]; *(float4*)sgv = *(const float4*)(sig + ycol);
            float yv[4];  *(float4*)yv  = *(const float4*)(yin + (size_t)yrow * NUc + ycol);
            float bb[4];  *(float4*)bb  = *(const float4*)(b2 + n0);
            int dest = (mode == 0) ? ((yrow < MH) ? 2 * yrow : 2 * yrow - (L_ROWS - 1))
                     : (mode == 1) ? (((yrow & 1) ? MH + (yrow >> 1) : (yrow >> 1)))
                     : yrow;
            float o[4];
            bf16x4 q;
#pragma unroll
            for (int r = 0; r < 4; ++r) {
                o[r] = sgv[r] * yv[r] + (acc[i][j][r] + bb[r]) * CW;
                q[r] = (__bf16)o[r];
            }
            *(float4*)(yout + (size_t)dest * NUc + ycol) = *(float4*)o;
            *(bf16x4*)(ybout + (size_t)dest * NUc + ycol) = q;
        }
    }
}

// ---------------------------------------------------------------- launch
extern "C" void kernel_launch(void* const* d_in, const int* in_sizes, int n_in,
                              void* d_out, int out_size, void* d_ws, size_t ws_size,
                              hipStream_t stream) {
    (void)in_sizes; (void)n_in; (void)out_size; (void)ws_size;
    const float* x    = (const float*)d_in[0];
    const float* rs_f = (const float*)d_in[1];
    const float* w1[3] = {(const float*)d_in[2], (const float*)d_in[6], (const float*)d_in[10]};
    const float* w2[3] = {(const float*)d_in[3], (const float*)d_in[7], (const float*)d_in[11]};
    const float* b2[3] = {(const float*)d_in[4], (const float*)d_in[8], (const float*)d_in[12]};
    const float* rs_r = (const float*)d_in[5];
    const float* rs_m = (const float*)d_in[9];

    // workspace layout (~84 MB)
    float*  y0    = (float*)d_ws;                          // 4M fp32
    float*  y1    = y0 + (size_t)MH * KIN;                 // 4M fp32
    bf16_t* yb    = (bf16_t*)(y1 + (size_t)MH * KIN);      // 4M bf16
    bf16_t* H     = yb + (size_t)MH * KIN;                 // 8M bf16
    bf16_t* w1t   = H + (size_t)MH * NH;                   // 3 x 2M bf16
    bf16_t* w2t   = w1t + 3 * (size_t)NH * KIN;            // 3 x 2M bf16
    float*  sig   = (float*)(w2t + 3 * (size_t)KIN * NH);  // 1536 fp32
    float*  stats = sig + 3 * NUc;                         // 25 x 2 x 2048 fp32

    init_misc<<<4096, 256, 0, stream>>>(x, yb, rs_f, rs_r, rs_m, sig, stats);
    for (int t = 0; t < 3; ++t) {
        transpose_f32_bf16<<<dim3(NH / 32, KIN / 32), 256, 0, stream>>>(w1[t], w1t + (size_t)t * NH * KIN, KIN, NH);
        transpose_f32_bf16<<<dim3(KIN / 32, NH / 32), 256, 0, stream>>>(w2[t], w2t + (size_t)t * KIN * NH, NH, KIN);
    }

    const float* cur = x;
    float* bufs[2] = {y0, y1};
    for (int u = 0; u < N_UNITS; ++u) {
        int tag  = (u < 12) ? 0 : (u < 24 ? 1 : 2);
        int mode = (u < 12) ? 0 : (u < 24 ? 1 : 2);
        float* st = stats + (size_t)u * 2 * NH;
        float* out = (u == N_UNITS - 1) ? (float*)d_out : bufs[u & 1];
        gemm1_kernel<<<dim3(NH / 64, MH / 128), 256, 0, stream>>>(
            yb, w1t + (size_t)tag * NH * KIN, H, st);
        norm_kernel<<<4096, 256, 0, stream>>>(H, st);
        gemm2_kernel<<<dim3(KIN / 64, MH / 128), 256, 0, stream>>>(
            H, w2t + (size_t)tag * KIN * NH, cur, out, yb,
            sig + tag * NUc, b2[tag], mode);
        cur = out;
    }
}